// Round 1
// baseline (24477.477 us; speedup 1.0000x reference)
//
#include <hip/hip_runtime.h>

// LightGCN: 3 x SpMM(scatter-add) + accumulate, then /4.
// Nodes = 300000, DIM = 64, NNZ = 9.6M.

constexpr int N_USERS_C = 100000;
constexpr int N_NODES_C = 300000;
constexpr int NNZ_C     = 9600000;
constexpr int DIM       = 64;
constexpr int TOT4      = N_NODES_C * DIM / 4;   // 4,800,000 float4 elems
constexpr int USER4     = N_USERS_C * DIM / 4;   // 1,600,000

// emb0 = concat(user, item); acc(d_out) = emb0
__global__ void __launch_bounds__(256) init_concat(
    const float4* __restrict__ user4,
    const float4* __restrict__ item4,
    float4* __restrict__ emb4,
    float4* __restrict__ acc4)
{
    int i = blockIdx.x * 256 + threadIdx.x;
    if (i >= TOT4) return;
    float4 v = (i < USER4) ? user4[i] : item4[i - USER4];
    emb4[i] = v;
    acc4[i] = v;
}

// Scatter SpMM: 16 threads per edge, each handles 4 dims (one float4).
// y[row*64 + d] += val * x[col*64 + d]
__global__ void __launch_bounds__(256) spmm_scatter(
    const int*   __restrict__ rows,
    const int*   __restrict__ cols,
    const float* __restrict__ vals,
    const float* __restrict__ x,
    float*       __restrict__ y)
{
    long long tid = (long long)blockIdx.x * 256 + threadIdx.x;
    int e = (int)(tid >> 4);
    if (e >= NNZ_C) return;
    int q = (int)(tid & 15);

    int   r = rows[e];
    int   c = cols[e];
    float v = vals[e];

    float4 xv = ((const float4*)x)[c * 16 + q];   // coalesced 256B per edge
    float* yp = y + (long long)r * DIM + q * 4;
    atomicAdd(yp + 0, v * xv.x);
    atomicAdd(yp + 1, v * xv.y);
    atomicAdd(yp + 2, v * xv.z);
    atomicAdd(yp + 3, v * xv.w);
}

// acc = (acc + nxt) * scale   (scale = 1 for mid layers, 0.25 for the last)
__global__ void __launch_bounds__(256) acc_add(
    const float4* __restrict__ nxt,
    float4* __restrict__ acc,
    float scale)
{
    int i = blockIdx.x * 256 + threadIdx.x;
    if (i >= TOT4) return;
    float4 a = acc[i];
    float4 n = nxt[i];
    a.x = (a.x + n.x) * scale;
    a.y = (a.y + n.y) * scale;
    a.z = (a.z + n.z) * scale;
    a.w = (a.w + n.w) * scale;
    acc[i] = a;
}

extern "C" void kernel_launch(void* const* d_in, const int* in_sizes, int n_in,
                              void* d_out, int out_size, void* d_ws, size_t ws_size,
                              hipStream_t stream)
{
    const int*   rows = (const int*)  d_in[0];
    const int*   cols = (const int*)  d_in[1];
    const float* vals = (const float*)d_in[2];
    const float* uemb = (const float*)d_in[3];
    const float* iemb = (const float*)d_in[4];
    float*       out  = (float*)d_out;

    const size_t embBytes = (size_t)N_NODES_C * DIM * sizeof(float); // 76.8 MB
    float* buf0 = (float*)d_ws;
    float* buf1 = (float*)((char*)d_ws + embBytes);

    const int gridE = (TOT4 + 255) / 256;                 // elementwise grids
    const long long sThreads = (long long)NNZ_C * 16;
    const int gridS = (int)((sThreads + 255) / 256);      // 600,000 blocks

    init_concat<<<gridE, 256, 0, stream>>>(
        (const float4*)uemb, (const float4*)iemb, (float4*)buf0, (float4*)out);

    float* cur = buf0;
    float* nxt = buf1;
    for (int layer = 0; layer < 3; ++layer) {
        hipMemsetAsync(nxt, 0, embBytes, stream);
        spmm_scatter<<<gridS, 256, 0, stream>>>(rows, cols, vals, cur, nxt);
        float scale = (layer == 2) ? 0.25f : 1.0f;
        acc_add<<<gridE, 256, 0, stream>>>((const float4*)nxt, (float4*)out, scale);
        float* t = cur; cur = nxt; nxt = t;
    }
}

// Round 2
// 2470.641 us; speedup vs baseline: 9.9073x; 9.9073x over previous
//
#include <hip/hip_runtime.h>

// LightGCN: 3 x SpMM + accumulate, /4.
// R1: device-side CSR build (hist + scan + scatter) -> pull-mode SpMM, no atomics
// in the hot loop. Falls back to R0 atomic-scatter path if ws too small.

constexpr int N_USERS_C = 100000;
constexpr int N_NODES_C = 300000;
constexpr int NNZ_C     = 9600000;
constexpr int DIM       = 64;
constexpr int TOT4      = N_NODES_C * DIM / 4;   // 4,800,000 float4
constexpr int USER4     = N_USERS_C * DIM / 4;   // 1,600,000

constexpr int SCAN_CHUNK = 1024;
constexpr int NBLK_SCAN  = (N_NODES_C + SCAN_CHUNK - 1) / SCAN_CHUNK; // 293

// ---------------- common ----------------

__global__ void __launch_bounds__(256) init_concat(
    const float4* __restrict__ user4,
    const float4* __restrict__ item4,
    float4* __restrict__ emb4,
    float4* __restrict__ acc4)
{
    int i = blockIdx.x * 256 + threadIdx.x;
    if (i >= TOT4) return;
    float4 v = (i < USER4) ? user4[i] : item4[i - USER4];
    emb4[i] = v;
    acc4[i] = v;
}

// ---------------- CSR build ----------------

__global__ void __launch_bounds__(256) hist_rows(
    const int* __restrict__ rows, int* __restrict__ counts)
{
    int e = blockIdx.x * 256 + threadIdx.x;
    if (e >= NNZ_C) return;
    atomicAdd(&counts[rows[e]], 1);
}

// block-level exclusive scan (256 threads x 4 items)
__global__ void __launch_bounds__(256) scan1(
    const int* __restrict__ counts, int* __restrict__ rowStart,
    int* __restrict__ blockSums)
{
    __shared__ int lds[256];
    int b = blockIdx.x, t = threadIdx.x;
    int base = b * SCAN_CHUNK;
    int v[4]; int s = 0;
    #pragma unroll
    for (int i = 0; i < 4; ++i) {
        int idx = base + t * 4 + i;
        v[i] = (idx < N_NODES_C) ? counts[idx] : 0;
        s += v[i];
    }
    lds[t] = s;
    __syncthreads();
    for (int off = 1; off < 256; off <<= 1) {
        int x = (t >= off) ? lds[t - off] : 0;
        __syncthreads();
        lds[t] += x;
        __syncthreads();
    }
    int excl = (t == 0) ? 0 : lds[t - 1];
    if (t == 255) blockSums[b] = lds[255];
    int run = excl;
    #pragma unroll
    for (int i = 0; i < 4; ++i) {
        int idx = base + t * 4 + i;
        if (idx < N_NODES_C) rowStart[idx] = run;
        run += v[i];
    }
}

__global__ void __launch_bounds__(512) scan2(
    const int* __restrict__ blockSums, int* __restrict__ blockOff)
{
    __shared__ int lds[512];
    int t = threadIdx.x;
    lds[t] = (t < NBLK_SCAN) ? blockSums[t] : 0;
    __syncthreads();
    for (int off = 1; off < 512; off <<= 1) {
        int x = (t >= off) ? lds[t - off] : 0;
        __syncthreads();
        lds[t] += x;
        __syncthreads();
    }
    if (t < NBLK_SCAN) blockOff[t] = (t == 0) ? 0 : lds[t - 1];
}

// rowStart += blockOff ; cursor = rowStart
__global__ void __launch_bounds__(256) scan3(
    int* __restrict__ rowStart, const int* __restrict__ blockOff,
    int* __restrict__ cursor)
{
    int i = blockIdx.x * 256 + threadIdx.x;
    if (i >= N_NODES_C) return;
    int v = rowStart[i] + blockOff[i >> 10];
    rowStart[i] = v;
    cursor[i]   = v;
}

__global__ void __launch_bounds__(256) scatter_edges(
    const int* __restrict__ rows, const int* __restrict__ cols,
    const float* __restrict__ vals, int* __restrict__ cursor,
    int2* __restrict__ packed)
{
    int e = blockIdx.x * 256 + threadIdx.x;
    if (e >= NNZ_C) return;
    int r = rows[e];
    int pos = atomicAdd(&cursor[r], 1);
    int2 p;
    p.x = cols[e];
    p.y = __float_as_int(vals[e]);
    packed[pos] = p;
}

// ---------------- pull-mode SpMM (fused acc update) ----------------
// 16 lanes per row; lane q owns dims [4q, 4q+4). tid == row*16 + q.
__global__ void __launch_bounds__(256) spmm_pull(
    const int2* __restrict__ packed,
    const int*  __restrict__ rowStart,
    const int*  __restrict__ counts,
    const float* __restrict__ x,
    float* __restrict__ y,
    float* __restrict__ acc,
    float scale)
{
    int tid = blockIdx.x * 256 + threadIdx.x;
    int row = tid >> 4;
    if (row >= N_NODES_C) return;
    int q = tid & 15;

    int s   = rowStart[row];
    int len = counts[row];
    const float4* x4 = (const float4*)x;

    float4 a = make_float4(0.f, 0.f, 0.f, 0.f);
    for (int e = s; e < s + len; ++e) {
        int2  p = packed[e];
        float v = __int_as_float(p.y);
        float4 xv = x4[p.x * 16 + q];
        a.x += v * xv.x;
        a.y += v * xv.y;
        a.z += v * xv.z;
        a.w += v * xv.w;
    }
    ((float4*)y)[tid] = a;
    float4 ac = ((float4*)acc)[tid];
    ac.x = (ac.x + a.x) * scale;
    ac.y = (ac.y + a.y) * scale;
    ac.z = (ac.z + a.z) * scale;
    ac.w = (ac.w + a.w) * scale;
    ((float4*)acc)[tid] = ac;
}

// ---------------- R0 fallback (atomic scatter) ----------------

__global__ void __launch_bounds__(256) spmm_scatter(
    const int*   __restrict__ rows,
    const int*   __restrict__ cols,
    const float* __restrict__ vals,
    const float* __restrict__ x,
    float*       __restrict__ y)
{
    long long tid = (long long)blockIdx.x * 256 + threadIdx.x;
    int e = (int)(tid >> 4);
    if (e >= NNZ_C) return;
    int q = (int)(tid & 15);
    int   r = rows[e];
    int   c = cols[e];
    float v = vals[e];
    float4 xv = ((const float4*)x)[c * 16 + q];
    float* yp = y + (long long)r * DIM + q * 4;
    atomicAdd(yp + 0, v * xv.x);
    atomicAdd(yp + 1, v * xv.y);
    atomicAdd(yp + 2, v * xv.z);
    atomicAdd(yp + 3, v * xv.w);
}

__global__ void __launch_bounds__(256) acc_add(
    const float4* __restrict__ nxt, float4* __restrict__ acc, float scale)
{
    int i = blockIdx.x * 256 + threadIdx.x;
    if (i >= TOT4) return;
    float4 a = acc[i];
    float4 n = nxt[i];
    a.x = (a.x + n.x) * scale;
    a.y = (a.y + n.y) * scale;
    a.z = (a.z + n.z) * scale;
    a.w = (a.w + n.w) * scale;
    acc[i] = a;
}

// ---------------- launch ----------------

extern "C" void kernel_launch(void* const* d_in, const int* in_sizes, int n_in,
                              void* d_out, int out_size, void* d_ws, size_t ws_size,
                              hipStream_t stream)
{
    const int*   rows = (const int*)  d_in[0];
    const int*   cols = (const int*)  d_in[1];
    const float* vals = (const float*)d_in[2];
    const float* uemb = (const float*)d_in[3];
    const float* iemb = (const float*)d_in[4];
    float*       out  = (float*)d_out;

    const size_t embBytes    = (size_t)N_NODES_C * DIM * sizeof(float);  // 76.8 MB
    const size_t packedBytes = (size_t)NNZ_C * sizeof(int2);             // 76.8 MB
    const size_t cntBytes    = (size_t)N_NODES_C * sizeof(int);          // 1.2 MB

    char* w = (char*)d_ws;
    size_t off = 0;
    float* buf0      = (float*)(w + off); off += embBytes;
    float* buf1      = (float*)(w + off); off += embBytes;
    int2*  packed    = (int2*) (w + off); off += packedBytes;
    int*   counts    = (int*)  (w + off); off += cntBytes;
    int*   rowStart  = (int*)  (w + off); off += cntBytes;
    int*   cursor    = (int*)  (w + off); off += cntBytes;
    int*   blockSums = (int*)  (w + off); off += 4096;
    int*   blockOff  = (int*)  (w + off); off += 4096;
    const size_t needed = off;

    const int gridE = (TOT4 + 255) / 256;            // elementwise
    const int gridN = (N_NODES_C + 255) / 256;       // per-node
    const int gridEdge = (NNZ_C + 255) / 256;        // per-edge
    const int gridPull = (N_NODES_C * 16) / 256;     // 18750

    init_concat<<<gridE, 256, 0, stream>>>(
        (const float4*)uemb, (const float4*)iemb, (float4*)buf0, (float4*)out);

    if (ws_size >= needed) {
        // ---- CSR build ----
        hipMemsetAsync(counts, 0, cntBytes, stream);
        hist_rows<<<gridEdge, 256, 0, stream>>>(rows, counts);
        scan1<<<NBLK_SCAN, 256, 0, stream>>>(counts, rowStart, blockSums);
        scan2<<<1, 512, 0, stream>>>(blockSums, blockOff);
        scan3<<<gridN, 256, 0, stream>>>(rowStart, blockOff, cursor);
        scatter_edges<<<gridEdge, 256, 0, stream>>>(rows, cols, vals, cursor, packed);

        // ---- 3 pull-mode layers, acc fused ----
        float* cur = buf0;
        float* nxt = buf1;
        for (int layer = 0; layer < 3; ++layer) {
            float scale = (layer == 2) ? 0.25f : 1.0f;
            spmm_pull<<<gridPull, 256, 0, stream>>>(
                packed, rowStart, counts, cur, nxt, out, scale);
            float* t = cur; cur = nxt; nxt = t;
        }
    } else {
        // ---- fallback: R0 atomic path (needs only 2*embBytes) ----
        const long long sThreads = (long long)NNZ_C * 16;
        const int gridS = (int)((sThreads + 255) / 256);
        float* cur = buf0;
        float* nxt = buf1;
        for (int layer = 0; layer < 3; ++layer) {
            hipMemsetAsync(nxt, 0, embBytes, stream);
            spmm_scatter<<<gridS, 256, 0, stream>>>(rows, cols, vals, cur, nxt);
            float scale = (layer == 2) ? 0.25f : 1.0f;
            acc_add<<<gridE, 256, 0, stream>>>((const float4*)nxt, (float4*)out, scale);
            float* t = cur; cur = nxt; nxt = t;
        }
    }
}